// Round 2
// baseline (615.639 us; speedup 1.0000x reference)
//
#include <hip/hip_runtime.h>
#include <stdint.h>

// Problem: B=8, Lq=Lv=2048, Din=Dout=512, all f32 in/out.
// out[b][l][0:512)=o, [512:1024)=q, [1024:1536)=mv broadcast.
// ws usage (~51.3 MB): qw bf16 | v bf16 | vT bf16 | kT bf16 | mv f32 | mv partial

typedef __attribute__((ext_vector_type(8))) short short8v;
typedef __attribute__((ext_vector_type(4))) float f32x4;

#define LQ 2048
#define LV 2048
#define DIN 512
#define DOUT 512
#define NB 8

__device__ __forceinline__ unsigned short f2bf(float x){
    union { float f; unsigned u; } v; v.f = x;
    unsigned r = v.u + 0x7fffu + ((v.u >> 16) & 1u);
    return (unsigned short)(r >> 16);
}

// kernel [DIN][DOUT] f32 -> kT [DOUT][DIN] bf16, scaled by 0.1 (folds the /10)
__global__ void prep_kT(const float* __restrict__ k, unsigned short* __restrict__ kT){
    __shared__ float tile[32][33];
    int tx = threadIdx.x & 31, ty = threadIdx.x >> 5;
    int kb = blockIdx.x, eb = blockIdx.y;
    #pragma unroll
    for (int p = 0; p < 4; ++p){
        int r = ty + p*8;
        tile[r][tx] = k[(size_t)(kb*32 + r)*DOUT + eb*32 + tx];
    }
    __syncthreads();
    #pragma unroll
    for (int p = 0; p < 4; ++p){
        int r = ty + p*8;
        kT[(size_t)(eb*32 + r)*DIN + kb*32 + tx] = f2bf(tile[tx][r] * 0.1f);
    }
}

// v f32 -> v bf16 (natural [b][j][e]) and vT bf16 ([b][e][j])
__global__ void prep_v(const float* __restrict__ v, unsigned short* __restrict__ vbf,
                       unsigned short* __restrict__ vT){
    __shared__ float tile[32][33];
    int tx = threadIdx.x & 31, ty = threadIdx.x >> 5;
    int jb = blockIdx.x, eb = blockIdx.y, b = blockIdx.z;
    const size_t vbase = (size_t)b*LV*DOUT;
    #pragma unroll
    for (int p = 0; p < 4; ++p){
        int r = ty + p*8;
        size_t idx = vbase + (size_t)(jb*32 + r)*DOUT + eb*32 + tx;
        float val = v[idx];
        tile[r][tx] = val;
        vbf[idx] = f2bf(val);
    }
    __syncthreads();
    const size_t tbase = (size_t)b*DOUT*LV;
    #pragma unroll
    for (int p = 0; p < 4; ++p){
        int r = ty + p*8;
        vT[tbase + (size_t)(eb*32 + r)*LV + jb*32 + tx] = f2bf(tile[tx][r]);
    }
}

// masked max over the value sequence, two-stage
__global__ void mv_partial(const float* __restrict__ v, const float* __restrict__ mask,
                           float* __restrict__ part){
    int b = blockIdx.x, ch = blockIdx.y;
    int e = threadIdx.x; // 512
    float m = -3e38f;
    for (int j = ch*128; j < ch*128 + 128; ++j){
        float msk = mask[b*LV + j];
        float val = v[((size_t)b*LV + j)*DOUT + e];
        m = fmaxf(m, val - (1.0f - msk)*1e10f);
    }
    part[((size_t)b*16 + ch)*DOUT + e] = m;
}

__global__ void mv_final(const float* __restrict__ part, float* __restrict__ mv){
    int b = blockIdx.x; int e = threadIdx.x;
    float m = -3e38f;
    #pragma unroll
    for (int c = 0; c < 16; ++c) m = fmaxf(m, part[((size_t)b*16 + c)*DOUT + e]);
    mv[b*DOUT + e] = m;
}

// qw[b*Lq+l][e] = sum_d q[..][d] * kT[e][d]  (bf16 MFMA, f32 acc, bf16 out)
__global__ __launch_bounds__(256) void gemm_qw(const float* __restrict__ q,
                                               const unsigned short* __restrict__ kT,
                                               unsigned short* __restrict__ qw){
    int bid = blockIdx.x;
    int mb = bid >> 1, nb = bid & 1;
    int w = threadIdx.x >> 6, lane = threadIdx.x & 63;
    int li = lane & 15, lg = lane >> 4;
    int i0 = mb*64 + w*16;
    int n0 = nb*256;
    f32x4 acc[16];
    #pragma unroll
    for (int t = 0; t < 16; ++t) acc[t] = (f32x4){0.f,0.f,0.f,0.f};
    for (int ks = 0; ks < 16; ++ks){
        const float* qp = q + (size_t)(i0 + li)*DIN + ks*32 + lg*8;
        float4 lo = *(const float4*)qp;
        float4 hi = *(const float4*)(qp + 4);
        short8v af;
        af[0]=(short)f2bf(lo.x); af[1]=(short)f2bf(lo.y); af[2]=(short)f2bf(lo.z); af[3]=(short)f2bf(lo.w);
        af[4]=(short)f2bf(hi.x); af[5]=(short)f2bf(hi.y); af[6]=(short)f2bf(hi.z); af[7]=(short)f2bf(hi.w);
        #pragma unroll
        for (int t = 0; t < 16; ++t){
            short8v bf = *(const short8v*)(kT + (size_t)(n0 + t*16 + li)*DIN + ks*32 + lg*8);
            acc[t] = __builtin_amdgcn_mfma_f32_16x16x32_bf16(af, bf, acc[t], 0, 0, 0);
        }
    }
    #pragma unroll
    for (int t = 0; t < 16; ++t)
        #pragma unroll
        for (int r = 0; r < 4; ++r)
            qw[(size_t)(i0 + 4*lg + r)*DOUT + n0 + t*16 + li] = f2bf(acc[t][r]);
}

// Flash attention v2: barrier-free main loop, 4-way KV split within block.
// Block = one 16-row q-tile; wave w owns KV range [w*512,(w+1)*512).
// V operands read DIRECT from global (L2-resident: 4 MB/batch, batch pinned
// to one XCD via b=bid&7). End-of-block softmax merge through LDS.
#define OBS 516   // Obuf row stride (floats): 4*516 % 32words -> <=2-way alias
__global__ __launch_bounds__(256, 2) void flash(const unsigned short* __restrict__ qw,
                                                const unsigned short* __restrict__ vbf,
                                                const unsigned short* __restrict__ vT,
                                                const float* __restrict__ mask,
                                                float* __restrict__ out){
    __shared__ float Obuf[16][OBS];          // 33 KB merge buffer
    __shared__ float red_m[4][16], red_s[4][16];
    __shared__ short P_lds[4][16][40];       // per-wave P repack (same-wave RAW only)

    int bid = blockIdx.x;
    int b = bid & 7;            // batch -> XCD pin (v stays in that XCD's L2)
    int qt = bid >> 3;
    int i0 = qt * 16;
    int tid = threadIdx.x;
    int w = tid >> 6, lane = tid & 63;
    int li = lane & 15, lg = lane >> 4;

    // q B-fragments: lane holds qw[i0+li][ks*32+lg*8 ..+7]
    short8v qf[16];
    const unsigned short* qrow = qw + (size_t)(b*LQ + i0 + li)*DIN;
    #pragma unroll
    for (int ks = 0; ks < 16; ++ks)
        qf[ks] = *(const short8v*)(qrow + ks*32 + lg*8);

    f32x4 accO[32];
    #pragma unroll
    for (int t = 0; t < 32; ++t) accO[t] = (f32x4){0.f,0.f,0.f,0.f};
    float mrun = -1e30f, srun = 0.0f;

    const unsigned short* vb  = vbf + (size_t)b*LV*DOUT;
    const unsigned short* vTb = vT  + (size_t)b*DOUT*LV;
    const float* mkb = mask + b*LV;

    int jt0 = w*16;
    for (int jt = jt0; jt < jt0 + 16; ++jt){
        int j0 = jt*32;

        // S^T tiles: D[m=j][n=i]; 4 split accumulator chains (dep depth 8 not 16)
        f32x4 s0a = (f32x4){0.f,0.f,0.f,0.f}, s0b = s0a, s1a = s0a, s1b = s0a;
        #pragma unroll
        for (int ks = 0; ks < 8; ++ks){
            short8v a0 = *(const short8v*)(vb + (size_t)(j0 + li)*DOUT + ks*32 + lg*8);
            s0a = __builtin_amdgcn_mfma_f32_16x16x32_bf16(a0, qf[ks], s0a, 0, 0, 0);
        }
        #pragma unroll
        for (int ks = 8; ks < 16; ++ks){
            short8v a0 = *(const short8v*)(vb + (size_t)(j0 + li)*DOUT + ks*32 + lg*8);
            s0b = __builtin_amdgcn_mfma_f32_16x16x32_bf16(a0, qf[ks], s0b, 0, 0, 0);
        }
        #pragma unroll
        for (int ks = 0; ks < 8; ++ks){
            short8v a1 = *(const short8v*)(vb + (size_t)(j0 + 16 + li)*DOUT + ks*32 + lg*8);
            s1a = __builtin_amdgcn_mfma_f32_16x16x32_bf16(a1, qf[ks], s1a, 0, 0, 0);
        }
        #pragma unroll
        for (int ks = 8; ks < 16; ++ks){
            short8v a1 = *(const short8v*)(vb + (size_t)(j0 + 16 + li)*DOUT + ks*32 + lg*8);
            s1b = __builtin_amdgcn_mfma_f32_16x16x32_bf16(a1, qf[ks], s1b, 0, 0, 0);
        }

        // mask bias, direct per-lane float4 loads (L1/L2 hits)
        f32x4 bm0 = *(const f32x4*)(mkb + j0 + 4*lg);
        f32x4 bm1 = *(const f32x4*)(mkb + j0 + 16 + 4*lg);

        float sv[8];
        #pragma unroll
        for (int r = 0; r < 4; ++r){
            sv[r]     = s0a[r] + s0b[r] + (bm0[r] - 1.0f)*1e10f;
            sv[4 + r] = s1a[r] + s1b[r] + (bm1[r] - 1.0f)*1e10f;
        }
        float pmax = sv[0];
        #pragma unroll
        for (int k = 1; k < 8; ++k) pmax = fmaxf(pmax, sv[k]);
        pmax = fmaxf(pmax, __shfl_xor(pmax, 16));
        pmax = fmaxf(pmax, __shfl_xor(pmax, 32));
        float mnew = fmaxf(mrun, pmax);
        float al = __expf(mrun - mnew);
        float p[8]; float psum = 0.f;
        #pragma unroll
        for (int k = 0; k < 8; ++k){ p[k] = __expf(sv[k] - mnew); psum += p[k]; }
        psum += __shfl_xor(psum, 16);
        psum += __shfl_xor(psum, 32);
        srun = srun*al + psum;
        mrun = mnew;

        if (!__all(al == 1.0f)){  // skip O-rescale when running max unchanged
            float alr[4];
            #pragma unroll
            for (int r = 0; r < 4; ++r) alr[r] = __shfl(al, 4*lg + r);
            #pragma unroll
            for (int t = 0; t < 32; ++t)
                #pragma unroll
                for (int r = 0; r < 4; ++r) accO[t][r] *= alr[r];
        }

        // pack P -> per-wave LDS [i=li][j], read PV A-fragment A[i=li][j=8*lg..+7]
        #pragma unroll
        for (int s2 = 0; s2 < 2; ++s2)
            #pragma unroll
            for (int k = 0; k < 2; ++k){
                unsigned lo2 = f2bf(p[s2*4 + 2*k]);
                unsigned hi2 = f2bf(p[s2*4 + 2*k + 1]);
                *(unsigned*)&P_lds[w][li][s2*16 + 4*lg + 2*k] = lo2 | (hi2 << 16);
            }
        short8v pa = *(const short8v*)&P_lds[w][li][lg*8];   // same-wave RAW

        // PV: B[k=j][n=e] = 16 contiguous bytes of global vT (L2-resident)
        #pragma unroll
        for (int t = 0; t < 32; ++t){
            short8v vf = *(const short8v*)(vTb + (size_t)(t*16 + li)*LV + j0 + lg*8);
            accO[t] = __builtin_amdgcn_mfma_f32_16x16x32_bf16(pa, vf, accO[t], 0, 0, 0);
        }
    }

    // ---- merge the 4 waves' partial (m, s, O) states ----
    if (lg == 0){ red_m[w][li] = mrun; red_s[w][li] = srun; }
    __syncthreads();

    float fw[4];
    #pragma unroll
    for (int r = 0; r < 4; ++r){
        int row = 4*lg + r;
        float mg = red_m[0][row];
        #pragma unroll
        for (int w2 = 1; w2 < 4; ++w2) mg = fmaxf(mg, red_m[w2][row]);
        float sg = 0.f;
        #pragma unroll
        for (int w2 = 0; w2 < 4; ++w2) sg += red_s[w2][row] * __expf(red_m[w2][row] - mg);
        fw[r] = __expf(red_m[w][row] - mg) / sg;   // includes final 1/s
    }

    #pragma unroll
    for (int step = 0; step < 4; ++step){
        if (w == step){
            #pragma unroll
            for (int t = 0; t < 32; ++t)
                #pragma unroll
                for (int r = 0; r < 4; ++r){
                    float val = fw[r]*accO[t][r];
                    if (step == 0) Obuf[4*lg + r][t*16 + li]  = val;
                    else           Obuf[4*lg + r][t*16 + li] += val;
                }
        }
        __syncthreads();
    }

    // cooperative writeout: 16 rows x 512 cols
    {
        int row = tid >> 4;
        int c0 = (tid & 15)*32;
        float* orow = out + (size_t)(b*LQ + i0 + row)*1536;
        #pragma unroll
        for (int k = 0; k < 8; ++k){
            float4 val = *(const float4*)&Obuf[row][c0 + k*4];
            *(float4*)(orow + c0 + k*4) = val;
        }
    }
}

// q passthrough + mv broadcast into out sections 1 and 2 (exact f32)
__global__ void copy_qmv(const float* __restrict__ q, const float* __restrict__ mv,
                         float* __restrict__ out){
    const float4* q4  = (const float4*)q;
    const float4* mv4 = (const float4*)mv;
    float4* o4 = (float4*)out;
    int total = NB*LQ*256;  // 256 float4 per row (128 q + 128 mv)
    for (int idx = blockIdx.x*blockDim.x + threadIdx.x; idx < total; idx += gridDim.x*blockDim.x){
        int c = idx & 255;
        int row = idx >> 8;       // b*LQ + l
        int b = row >> 11;
        if (c < 128) o4[(size_t)row*384 + 128 + c] = q4[(size_t)row*128 + c];
        else         o4[(size_t)row*384 + 128 + c] = mv4[b*128 + (c - 128)];
    }
}

extern "C" void kernel_launch(void* const* d_in, const int* in_sizes, int n_in,
                              void* d_out, int out_size, void* d_ws, size_t ws_size,
                              hipStream_t stream){
    const float* q     = (const float*)d_in[0];
    const float* v     = (const float*)d_in[1];
    const float* vmask = (const float*)d_in[2];
    const float* kern  = (const float*)d_in[3];
    float* out = (float*)d_out;
    char* ws = (char*)d_ws;

    const size_t SZ_QW = (size_t)NB*LQ*DOUT*2;   // 16 MB
    unsigned short* qw  = (unsigned short*)(ws);
    unsigned short* vbf = (unsigned short*)(ws + SZ_QW);
    unsigned short* vT  = (unsigned short*)(ws + 2*SZ_QW);
    unsigned short* kT  = (unsigned short*)(ws + 3*SZ_QW);
    float* mv   = (float*)(ws + 3*SZ_QW + 524288);
    float* part = (float*)(ws + 3*SZ_QW + 524288 + 16384);

    hipLaunchKernelGGL(prep_kT,   dim3(16,16),   dim3(256), 0, stream, kern, kT);
    hipLaunchKernelGGL(prep_v,    dim3(64,16,8), dim3(256), 0, stream, v, vbf, vT);
    hipLaunchKernelGGL(mv_partial,dim3(8,16),    dim3(512), 0, stream, v, vmask, part);
    hipLaunchKernelGGL(mv_final,  dim3(8),       dim3(512), 0, stream, part, mv);
    hipLaunchKernelGGL(gemm_qw,   dim3(512),     dim3(256), 0, stream, q, kT, qw);
    hipLaunchKernelGGL(flash,     dim3(1024),    dim3(256), 0, stream, qw, vbf, vT, vmask, out);
    hipLaunchKernelGGL(copy_qmv,  dim3(2048),    dim3(256), 0, stream, q, mv, out);
}

// Round 3
// 305.203 us; speedup vs baseline: 2.0171x; 2.0171x over previous
//
#include <hip/hip_runtime.h>
#include <stdint.h>

// Problem: B=8, Lq=Lv=2048, Din=Dout=512, all f32 in/out.
// out[b][l][0:512)=o, [512:1024)=q, [1024:1536)=mv broadcast.

typedef __attribute__((ext_vector_type(8))) short short8v;
typedef __attribute__((ext_vector_type(4))) float f32x4;

#define LQ 2048
#define LV 2048
#define DIN 512
#define DOUT 512
#define NB 8
#define KT 32   // KV tile

__device__ __forceinline__ unsigned short f2bf(float x){
    union { float f; unsigned u; } v; v.f = x;
    unsigned r = v.u + 0x7fffu + ((v.u >> 16) & 1u);
    return (unsigned short)(r >> 16);
}

// async global->LDS, 16B per lane; LDS dest = wave-uniform base + lane*16
__device__ __forceinline__ void gload16(const void* g, void* l){
    __builtin_amdgcn_global_load_lds((const __attribute__((address_space(1))) void*)g,
                                     (__attribute__((address_space(3))) void*)l, 16, 0, 0);
}

// kernel [DIN][DOUT] f32 -> kT [DOUT][DIN] bf16, scaled by 0.1 (folds the /10)
__global__ void prep_kT(const float* __restrict__ k, unsigned short* __restrict__ kT){
    __shared__ float tile[32][33];
    int tx = threadIdx.x & 31, ty = threadIdx.x >> 5;
    int kb = blockIdx.x, eb = blockIdx.y;
    #pragma unroll
    for (int p = 0; p < 4; ++p){
        int r = ty + p*8;
        tile[r][tx] = k[(size_t)(kb*32 + r)*DOUT + eb*32 + tx];
    }
    __syncthreads();
    #pragma unroll
    for (int p = 0; p < 4; ++p){
        int r = ty + p*8;
        kT[(size_t)(eb*32 + r)*DIN + kb*32 + tx] = f2bf(tile[tx][r] * 0.1f);
    }
}

// v f32 -> vbf bf16 [b][j][e], vT bf16 [b][e][j]; fused masked-max partials
__global__ void prep_v(const float* __restrict__ v, const float* __restrict__ mask,
                       unsigned short* __restrict__ vbf, unsigned short* __restrict__ vT,
                       float* __restrict__ part){
    __shared__ float tile[32][33];
    __shared__ float pmax_l[8][33];
    int tx = threadIdx.x & 31, ty = threadIdx.x >> 5;
    int jb = blockIdx.x, eb = blockIdx.y, b = blockIdx.z;
    const size_t vbase = (size_t)b*LV*DOUT;
    #pragma unroll
    for (int p = 0; p < 4; ++p){
        int r = ty + p*8;
        size_t idx = vbase + (size_t)(jb*32 + r)*DOUT + eb*32 + tx;
        float val = v[idx];
        tile[r][tx] = val;
        vbf[idx] = f2bf(val);
    }
    __syncthreads();
    const size_t tbase = (size_t)b*DOUT*LV;
    #pragma unroll
    for (int p = 0; p < 4; ++p){
        int r = ty + p*8;
        vT[tbase + (size_t)(eb*32 + r)*LV + jb*32 + tx] = f2bf(tile[tx][r]);
    }
    // masked max over this tile's 32 j for each of 32 e
    float m = -3e38f;
    #pragma unroll
    for (int k2 = 0; k2 < 4; ++k2){
        int j = ty*4 + k2;
        float msk = mask[b*LV + jb*32 + j];
        m = fmaxf(m, tile[j][tx] - (1.0f - msk)*1e10f);
    }
    pmax_l[ty][tx] = m;
    __syncthreads();
    if (ty == 0){
        float mm = pmax_l[0][tx];
        #pragma unroll
        for (int c = 1; c < 8; ++c) mm = fmaxf(mm, pmax_l[c][tx]);
        part[((size_t)b*64 + jb)*DOUT + eb*32 + tx] = mm;
    }
}

__global__ void mv_final(const float* __restrict__ part, float* __restrict__ mv){
    int b = blockIdx.x; int e = threadIdx.x;
    float m = -3e38f;
    #pragma unroll
    for (int c = 0; c < 64; ++c) m = fmaxf(m, part[((size_t)b*64 + c)*DOUT + e]);
    mv[b*DOUT + e] = m;
}

// qw[b*Lq+l][e] = sum_d q[..][d] * kT[e][d]  (bf16 MFMA, f32 acc, bf16 out)
__global__ __launch_bounds__(256) void gemm_qw(const float* __restrict__ q,
                                               const unsigned short* __restrict__ kT,
                                               unsigned short* __restrict__ qw){
    int bid = blockIdx.x;
    int mb = bid >> 1, nb = bid & 1;
    int w = threadIdx.x >> 6, lane = threadIdx.x & 63;
    int li = lane & 15, lg = lane >> 4;
    int i0 = mb*64 + w*16;
    int n0 = nb*256;
    f32x4 acc[16];
    #pragma unroll
    for (int t = 0; t < 16; ++t) acc[t] = (f32x4){0.f,0.f,0.f,0.f};
    for (int ks = 0; ks < 16; ++ks){
        const float* qp = q + (size_t)(i0 + li)*DIN + ks*32 + lg*8;
        float4 lo = *(const float4*)qp;
        float4 hi = *(const float4*)(qp + 4);
        short8v af;
        af[0]=(short)f2bf(lo.x); af[1]=(short)f2bf(lo.y); af[2]=(short)f2bf(lo.z); af[3]=(short)f2bf(lo.w);
        af[4]=(short)f2bf(hi.x); af[5]=(short)f2bf(hi.y); af[6]=(short)f2bf(hi.z); af[7]=(short)f2bf(hi.w);
        #pragma unroll
        for (int t = 0; t < 16; ++t){
            short8v bf = *(const short8v*)(kT + (size_t)(n0 + t*16 + li)*DIN + ks*32 + lg*8);
            acc[t] = __builtin_amdgcn_mfma_f32_16x16x32_bf16(af, bf, acc[t], 0, 0, 0);
        }
    }
    #pragma unroll
    for (int t = 0; t < 16; ++t)
        #pragma unroll
        for (int r = 0; r < 4; ++r)
            qw[(size_t)(i0 + 4*lg + r)*DOUT + n0 + t*16 + li] = f2bf(acc[t][r]);
}

// Flash v3: 4 waves x 16 q-rows share KV tiles staged via async global_load_lds
// into double-buffered LDS (1 barrier/tile). A-tile [32j][512d] XOR-swizzled
// (pre-swizzled global source, swizzled ds_read); T-tile [512e][32j] linear.
// Each wave keeps complete softmax state -> no merge phase.
__global__ __launch_bounds__(256, 1) void flash(const unsigned short* __restrict__ qw,
                                                const unsigned short* __restrict__ vbf,
                                                const unsigned short* __restrict__ vT,
                                                const float* __restrict__ mask,
                                                float* __restrict__ out){
    __shared__ __align__(16) short A_t[2][KT*512];   // 2x32KB, [j][d] swizzled
    __shared__ __align__(16) short T_t[2][512*KT];   // 2x32KB, [e][j] linear
    __shared__ short P_lds[4][16][40];

    const int bid = blockIdx.x;
    const int b = bid & 7, qt = bid >> 3;   // batch -> XCD pin
    const int tid = threadIdx.x;
    const int w = tid >> 6, lane = tid & 63;
    const int li = lane & 15, lg = lane >> 4;
    const int i0 = qt*64 + w*16;

    const unsigned short* vb  = vbf + (size_t)b*LV*DOUT;
    const unsigned short* vTb = vT  + (size_t)b*DOUT*LV;
    const float* mkb = mask + b*LV;

    // prologue: stage tile 0 into buffer 0
    #pragma unroll
    for (int p = 0; p < 8; ++p){
        int j = w*8 + p;
        gload16(vb + (size_t)j*DOUT + ((lane ^ (j&7))*8), &A_t[0][j*512]);
    }
    #pragma unroll
    for (int p = 0; p < 8; ++p){
        int e = w*128 + p*16 + (lane >> 2);
        gload16(vTb + (size_t)e*LV + (lane&3)*8, &T_t[0][(w*128 + p*16)*KT]);
    }

    // q B-fragments: lane holds qw[i0+li][ks*32+lg*8 ..+7]
    short8v qf[16];
    const unsigned short* qrow = qw + (size_t)(b*LQ + i0 + li)*DIN;
    #pragma unroll
    for (int ks = 0; ks < 16; ++ks)
        qf[ks] = *(const short8v*)(qrow + ks*32 + lg*8);

    f32x4 accO[32];
    #pragma unroll
    for (int t = 0; t < 32; ++t) accO[t] = (f32x4){0.f,0.f,0.f,0.f};
    float mrun = -1e30f, srun = 0.0f;

    __syncthreads();   // compiler drains vmcnt before barrier

    const int key = li & 7;
    for (int jt = 0; jt < 64; ++jt){
        const int cur = jt & 1;
        const short* Ac = A_t[cur];
        const short* Tc = T_t[cur];

        // issue next tile's async stage first (flies under this tile's compute)
        if (jt + 1 < 64){
            const int j0n = (jt+1)*KT;
            const int nb2 = cur ^ 1;
            #pragma unroll
            for (int p = 0; p < 8; ++p){
                int j = w*8 + p;
                gload16(vb + (size_t)(j0n + j)*DOUT + ((lane ^ (j&7))*8), &A_t[nb2][j*512]);
            }
            #pragma unroll
            for (int p = 0; p < 8; ++p){
                int e = w*128 + p*16 + (lane >> 2);
                gload16(vTb + (size_t)e*LV + j0n + (lane&3)*8, &T_t[nb2][(w*128 + p*16)*KT]);
            }
        }
        const int j0 = jt*KT;

        // S^T tiles from swizzled A: row j0+{li, li+16}, unit (ks*4+lg)^key
        f32x4 s0a = (f32x4){0.f,0.f,0.f,0.f}, s0b = s0a, s1a = s0a, s1b = s0a;
        #pragma unroll
        for (int ks = 0; ks < 8; ++ks){
            short8v a = *(const short8v*)&Ac[li*512 + (((ks*4 + lg)^key)*8)];
            s0a = __builtin_amdgcn_mfma_f32_16x16x32_bf16(a, qf[ks], s0a, 0, 0, 0);
        }
        #pragma unroll
        for (int ks = 8; ks < 16; ++ks){
            short8v a = *(const short8v*)&Ac[li*512 + (((ks*4 + lg)^key)*8)];
            s0b = __builtin_amdgcn_mfma_f32_16x16x32_bf16(a, qf[ks], s0b, 0, 0, 0);
        }
        #pragma unroll
        for (int ks = 0; ks < 8; ++ks){
            short8v a = *(const short8v*)&Ac[(li+16)*512 + (((ks*4 + lg)^key)*8)];
            s1a = __builtin_amdgcn_mfma_f32_16x16x32_bf16(a, qf[ks], s1a, 0, 0, 0);
        }
        #pragma unroll
        for (int ks = 8; ks < 16; ++ks){
            short8v a = *(const short8v*)&Ac[(li+16)*512 + (((ks*4 + lg)^key)*8)];
            s1b = __builtin_amdgcn_mfma_f32_16x16x32_bf16(a, qf[ks], s1b, 0, 0, 0);
        }

        // mask bias (direct L1/L2 hits)
        f32x4 bm0 = *(const f32x4*)(mkb + j0 + 4*lg);
        f32x4 bm1 = *(const f32x4*)(mkb + j0 + 16 + 4*lg);

        float sv[8];
        #pragma unroll
        for (int r = 0; r < 4; ++r){
            sv[r]     = s0a[r] + s0b[r] + (bm0[r] - 1.0f)*1e10f;
            sv[4 + r] = s1a[r] + s1b[r] + (bm1[r] - 1.0f)*1e10f;
        }
        float pmax = sv[0];
        #pragma unroll
        for (int k = 1; k < 8; ++k) pmax = fmaxf(pmax, sv[k]);
        pmax = fmaxf(pmax, __shfl_xor(pmax, 16));
        pmax = fmaxf(pmax, __shfl_xor(pmax, 32));
        float mnew = fmaxf(mrun, pmax);
        float al = __expf(mrun - mnew);
        float p[8]; float psum = 0.f;
        #pragma unroll
        for (int k = 0; k < 8; ++k){ p[k] = __expf(sv[k] - mnew); psum += p[k]; }
        psum += __shfl_xor(psum, 16);
        psum += __shfl_xor(psum, 32);
        srun = srun*al + psum;
        mrun = mnew;

        if (!__all(al == 1.0f)){  // skip O-rescale when running max unchanged
            float alr[4];
            #pragma unroll
            for (int r = 0; r < 4; ++r) alr[r] = __shfl(al, 4*lg + r);
            #pragma unroll
            for (int t = 0; t < 32; ++t)
                #pragma unroll
                for (int r = 0; r < 4; ++r) accO[t][r] *= alr[r];
        }

        // pack P -> per-wave LDS [i=li][j], read PV A-fragment A[i=li][j=8*lg..+7]
        #pragma unroll
        for (int s2 = 0; s2 < 2; ++s2)
            #pragma unroll
            for (int k = 0; k < 2; ++k){
                unsigned lo2 = f2bf(p[s2*4 + 2*k]);
                unsigned hi2 = f2bf(p[s2*4 + 2*k + 1]);
                *(unsigned*)&P_lds[w][li][s2*16 + 4*lg + 2*k] = lo2 | (hi2 << 16);
            }
        short8v pa = *(const short8v*)&P_lds[w][li][lg*8];   // same-wave RAW

        // PV from T-tile: B[k=j][n=e], row e=t*16+li, k-span lg*8..+7
        #pragma unroll
        for (int t = 0; t < 32; ++t){
            short8v vf = *(const short8v*)&Tc[(t*16 + li)*KT + lg*8];
            accO[t] = __builtin_amdgcn_mfma_f32_16x16x32_bf16(pa, vf, accO[t], 0, 0, 0);
        }

        __syncthreads();   // next-tile stage complete + this tile's reads done
    }

    // epilogue: per-wave complete state, direct writeout
    float inv[4];
    #pragma unroll
    for (int r = 0; r < 4; ++r) inv[r] = 1.0f / __shfl(srun, 4*lg + r);
    #pragma unroll
    for (int t = 0; t < 32; ++t)
        #pragma unroll
        for (int r = 0; r < 4; ++r)
            out[(size_t)(b*LQ + i0 + 4*lg + r)*1536 + t*16 + li] = accO[t][r]*inv[r];
}

// q passthrough + mv broadcast into out sections 1 and 2 (exact f32)
__global__ void copy_qmv(const float* __restrict__ q, const float* __restrict__ mv,
                         float* __restrict__ out){
    const float4* q4  = (const float4*)q;
    const float4* mv4 = (const float4*)mv;
    float4* o4 = (float4*)out;
    int total = NB*LQ*256;  // 256 float4 per row (128 q + 128 mv)
    for (int idx = blockIdx.x*blockDim.x + threadIdx.x; idx < total; idx += gridDim.x*blockDim.x){
        int c = idx & 255;
        int row = idx >> 8;       // b*LQ + l
        int b = row >> 11;
        if (c < 128) o4[(size_t)row*384 + 128 + c] = q4[(size_t)row*128 + c];
        else         o4[(size_t)row*384 + 128 + c] = mv4[b*128 + (c - 128)];
    }
}

extern "C" void kernel_launch(void* const* d_in, const int* in_sizes, int n_in,
                              void* d_out, int out_size, void* d_ws, size_t ws_size,
                              hipStream_t stream){
    const float* q     = (const float*)d_in[0];
    const float* v     = (const float*)d_in[1];
    const float* vmask = (const float*)d_in[2];
    const float* kern  = (const float*)d_in[3];
    float* out = (float*)d_out;
    char* ws = (char*)d_ws;

    const size_t SZ_QW = (size_t)NB*LQ*DOUT*2;   // 16 MB
    unsigned short* qw  = (unsigned short*)(ws);
    unsigned short* vbf = (unsigned short*)(ws + SZ_QW);
    unsigned short* vT  = (unsigned short*)(ws + 2*SZ_QW);
    unsigned short* kT  = (unsigned short*)(ws + 3*SZ_QW);
    float* mv   = (float*)(ws + 3*SZ_QW + 524288);
    float* part = (float*)(ws + 3*SZ_QW + 524288 + 16384);

    hipLaunchKernelGGL(prep_kT,   dim3(16,16),   dim3(256), 0, stream, kern, kT);
    hipLaunchKernelGGL(prep_v,    dim3(64,16,8), dim3(256), 0, stream, v, vmask, vbf, vT, part);
    hipLaunchKernelGGL(mv_final,  dim3(8),       dim3(512), 0, stream, part, mv);
    hipLaunchKernelGGL(gemm_qw,   dim3(512),     dim3(256), 0, stream, q, kT, qw);
    hipLaunchKernelGGL(flash,     dim3(256),     dim3(256), 0, stream, qw, vbf, vT, vmask, out);
    hipLaunchKernelGGL(copy_qmv,  dim3(2048),    dim3(256), 0, stream, q, mv, out);
}